// Round 5
// baseline (156.499 us; speedup 1.0000x reference)
//
#include <hip/hip_runtime.h>
#include <math.h>

#define EPS 1e-8f

__device__ __forceinline__ float wredsum(float v) {
#pragma unroll
  for (int o = 32; o > 0; o >>= 1) v += __shfl_down(v, o, 64);
  return v;  // valid in lane 0
}

// 8 consecutive k-steps of a 4-col FMA: c += x[k] * w[k][0..3]
__device__ __forceinline__ void fma8(const float4* w, const float4 a,
                                     const float4 b, float4& c) {
  const float xs[8] = {a.x, a.y, a.z, a.w, b.x, b.y, b.z, b.w};
#pragma unroll
  for (int i = 0; i < 8; ++i) {
    c.x = fmaf(xs[i], w[i].x, c.x);
    c.y = fmaf(xs[i], w[i].y, c.y);
    c.z = fmaf(xs[i], w[i].z, c.z);
    c.w = fmaf(xs[i], w[i].w, c.w);
  }
}

// ---------------- Layer 1: [11,8192] @ [8192,512] -> 32 k-chunk partials -----
// FROZEN from previous round (minus unused barrier init).
// grid (16 col-tiles of 32, 32 k-chunks of 256) = 512 blocks, 2/CU.
__global__ __launch_bounds__(256, 2) void k_l1(const float* __restrict__ xn,
                                               const float* __restrict__ xe,
                                               const float* __restrict__ W1,
                                               float* __restrict__ p1) {
  __shared__ float red[11 * 32 * 36];  // 50688 B
  const int cg  = threadIdx.x & 7;
  const int ks  = threadIdx.x >> 3;
  const int col = blockIdx.x * 32 + cg * 4;
  const int k0  = blockIdx.y * 256 + ks * 8;

  float4 w[8];
#pragma unroll
  for (int i = 0; i < 8; ++i)
    w[i] = *(const float4*)&W1[(size_t)(k0 + i) * 512 + col];

  float4 acc[11];
#pragma unroll
  for (int r = 0; r < 11; ++r) acc[r] = make_float4(0.f, 0.f, 0.f, 0.f);

  {
    const float4 a = *(const float4*)&xn[k0];
    const float4 b = *(const float4*)&xn[k0 + 4];
    fma8(w, a, b, acc[0]);
  }
#pragma unroll
  for (int r = 0; r < 10; ++r) {
    const float4 a = *(const float4*)&xe[r * 8192 + k0];
    const float4 b = *(const float4*)&xe[r * 8192 + k0 + 4];
    fma8(w, a, b, acc[r + 1]);
  }

#pragma unroll
  for (int r = 0; r < 11; ++r)
    *(float4*)&red[(r * 32 + ks) * 36 + cg * 4] = acc[r];
  __syncthreads();

  for (int o = threadIdx.x; o < 352; o += 256) {
    const int r = o >> 5, c = o & 31;
    float s = 0.f;
#pragma unroll
    for (int k = 0; k < 32; ++k) s += red[(r * 32 + k) * 36 + c];
    p1[((size_t)blockIdx.y * 11 + r) * 512 + blockIdx.x * 32 + c] = s;
  }
}

// ---------------- Tail: ONE block x 1024. Zero device-scope hops. ------------
// All intermediates in LDS; k-group reductions via in-wave shfl (k-groups in
// adjacent lanes); H1/H2 stored k-interleaved so k-group-parallel LDS reads
// hit consecutive banks (conflict-free).
__global__ __launch_bounds__(1024) void k_tail1(
    const float* __restrict__ p1, const float* __restrict__ b1,
    const float* __restrict__ W2, const float* __restrict__ b2,
    const float* __restrict__ W3, const float* __restrict__ b3,
    const float* __restrict__ mm,
    const float* __restrict__ Wi1, const float* __restrict__ bi1,
    const float* __restrict__ Wi2, const float* __restrict__ bi2,
    const float* __restrict__ Wi3, const float* __restrict__ bi3,
    float* __restrict__ out) {
  __shared__ float h1[5632];   // 22528 B, k-interleaved: [r*512 + (k&127)*4 + (k>>7)]
  __shared__ float h2[2816];   // 11264 B, k-interleaved: [r*256 + (k&31)*8 + (k>>5)]
  __shared__ float encs[1408]; //  5632 B
  __shared__ float comb[134];
  __shared__ float h1b[64];
  const int t = threadIdx.x;   // total static LDS ~40 KB

  // ---- T1: H1 = relu(b1 + sum_ch p1)  (reads p1, 720 KB) ----
  for (int o = t; o < 5632; o += 1024) {
    const int col = o & 511;
    float s = b1[col];
#pragma unroll 8
    for (int ch = 0; ch < 32; ++ch) s += p1[(size_t)ch * 5632 + o];
    h1[(o & ~511) | ((col & 127) << 2) | (col >> 7)] = fmaxf(s, 0.f);
  }
  __syncthreads();

  // ---- T2: H2 = relu(H1 @ W2 + b2). 256 cols x 4 k-groups (adjacent lanes) --
  {
    const int col = t >> 2, kg = t & 3;  // k-group in lanes 0..3 of each quad
    float acc[11];
#pragma unroll
    for (int r = 0; r < 11; ++r) acc[r] = 0.f;
#pragma unroll 8
    for (int kk = 0; kk < 128; ++kk) {
      const int k = kg * 128 + kk;
      const float w = W2[(size_t)k * 256 + col];
      const int hk = (kk << 2) | kg;  // interleaved index, 4 consecutive banks
#pragma unroll
      for (int r = 0; r < 11; ++r) acc[r] = fmaf(h1[r * 512 + hk], w, acc[r]);
    }
    const float bb = b2[col];
#pragma unroll
    for (int r = 0; r < 11; ++r) {
      float v = acc[r];
      v += __shfl_down(v, 1, 64);
      v += __shfl_down(v, 2, 64);
      if (kg == 0)
        h2[r * 256 + ((col & 31) << 3) + (col >> 5)] = fmaxf(v + bb, 0.f);
    }
  }
  __syncthreads();

  // ---- T3: enc = H2 @ W3 + b3. 128 cols x 8 k-groups (adjacent lanes) -------
  {
    const int c = t >> 3, kg = t & 7;
    float acc[11];
#pragma unroll
    for (int r = 0; r < 11; ++r) acc[r] = 0.f;
#pragma unroll 4
    for (int kk = 0; kk < 32; ++kk) {
      const int k = kg * 32 + kk;
      const float w = W3[(size_t)k * 128 + c];
      const int hk = (kk << 3) | kg;  // interleaved, 8 consecutive banks
#pragma unroll
      for (int r = 0; r < 11; ++r) acc[r] = fmaf(h2[r * 256 + hk], w, acc[r]);
    }
    const float bb = b3[c];
#pragma unroll
    for (int r = 0; r < 11; ++r) {
      float v = acc[r];
      v += __shfl_down(v, 1, 64);
      v += __shfl_down(v, 2, 64);
      v += __shfl_down(v, 4, 64);
      if (kg == 0) encs[r * 128 + c] = v + bb;
    }
  }
  __syncthreads();

  // ---- T4: similarity (wave 0) || integrator layer 1 (wave 1) ---------------
  float consist = 0.f;
  float n0 = 0.f, n1 = 0.f;
  if (t < 64) {
    n0 = encs[t]; n1 = encs[64 + t];
    comb[t] = n0; comb[64 + t] = n1;
    if (t < 6) comb[128 + t] = mm[t];
  }
  __syncthreads();  // comb ready
  if (t < 64) {
    const float nn = wredsum(n0 * n0 + n1 * n1);
#pragma unroll
    for (int r = 1; r <= 10; ++r) {
      const float e0 = encs[r * 128 + t];
      const float e1 = encs[r * 128 + 64 + t];
      const float d0 = e0 - n0, d1 = e1 - n1;
      const float g  = wredsum(d0 * d0 + d1 * d1);
      const float q  = wredsum(e0 * e0 + e1 * e1);
      const float dd = wredsum(e0 * n0 + e1 * n1);
      if (t == 0) {
        const float geo = sqrtf(g);
        const float den = fmaxf(sqrtf(nn), EPS) * fmaxf(sqrtf(q), EPS);
        consist += geo - dd / den;
      }
    }
  } else if (t < 128) {
    const int tt = t - 64;
    float h = bi1[tt];
#pragma unroll 4
    for (int k = 0; k < 134; ++k) h = fmaf(comb[k], Wi1[(size_t)k * 64 + tt], h);
    h1b[tt] = fmaxf(h, 0.f);
  }
  __syncthreads();
  if (t < 64) {
    float part = 0.f;
    if (t < 32) {
      float hh = bi2[t];
#pragma unroll 8
      for (int k = 0; k < 64; ++k) hh = fmaf(h1b[k], Wi2[k * 32 + t], hh);
      part = fmaxf(hh, 0.f) * Wi3[t];
    }
    const float qual = wredsum(part);
    if (t == 0) out[0] = consist * 0.1f + expf(-(qual + bi3[0]));
  }
}

extern "C" void kernel_launch(void* const* d_in, const int* in_sizes, int n_in,
                              void* d_out, int out_size, void* d_ws, size_t ws_size,
                              hipStream_t stream) {
  (void)in_sizes; (void)n_in; (void)out_size; (void)ws_size;
  const float* xn  = (const float*)d_in[0];
  const float* xe  = (const float*)d_in[1];
  const float* mm  = (const float*)d_in[2];
  const float* W1  = (const float*)d_in[3];
  const float* b1  = (const float*)d_in[4];
  const float* W2  = (const float*)d_in[5];
  const float* b2  = (const float*)d_in[6];
  const float* W3  = (const float*)d_in[7];
  const float* b3  = (const float*)d_in[8];
  const float* Wi1 = (const float*)d_in[9];
  const float* bi1 = (const float*)d_in[10];
  const float* Wi2 = (const float*)d_in[11];
  const float* bi2 = (const float*)d_in[12];
  const float* Wi3 = (const float*)d_in[13];
  const float* bi3 = (const float*)d_in[14];
  float* out = (float*)d_out;

  float* p1 = (float*)d_ws;  // 32*11*512*4 = 720896 B

  hipLaunchKernelGGL(k_l1,    dim3(16, 32), dim3(256),  0, stream, xn, xe, W1, p1);
  hipLaunchKernelGGL(k_tail1, dim3(1),      dim3(1024), 0, stream,
                     p1, b1, W2, b2, W3, b3, mm,
                     Wi1, bi1, Wi2, bi2, Wi3, bi3, out);
}

// Round 6
// 126.995 us; speedup vs baseline: 1.2323x; 1.2323x over previous
//
#include <hip/hip_runtime.h>
#include <math.h>

#define EPS 1e-8f

__device__ __forceinline__ float wredsum(float v) {
#pragma unroll
  for (int o = 32; o > 0; o >>= 1) v += __shfl_down(v, o, 64);
  return v;  // valid in lane 0
}

// 8 consecutive k-steps of a 4-col FMA: c += x[k] * w[k][0..3]
__device__ __forceinline__ void fma8(const float4* w, const float4 a,
                                     const float4 b, float4& c) {
  const float xs[8] = {a.x, a.y, a.z, a.w, b.x, b.y, b.z, b.w};
#pragma unroll
  for (int i = 0; i < 8; ++i) {
    c.x = fmaf(xs[i], w[i].x, c.x);
    c.y = fmaf(xs[i], w[i].y, c.y);
    c.z = fmaf(xs[i], w[i].z, c.z);
    c.w = fmaf(xs[i], w[i].w, c.w);
  }
}

// ---------------- Layer 1: [11,8192] @ [8192,512] -> 32 k-chunk partials -----
// FROZEN (R4). grid (16 col-tiles of 32, 32 k-chunks of 256) = 512 blocks.
__global__ __launch_bounds__(256, 2) void k_l1(const float* __restrict__ xn,
                                               const float* __restrict__ xe,
                                               const float* __restrict__ W1,
                                               float* __restrict__ p1) {
  __shared__ float red[11 * 32 * 36];  // 50688 B
  const int cg  = threadIdx.x & 7;
  const int ks  = threadIdx.x >> 3;
  const int col = blockIdx.x * 32 + cg * 4;
  const int k0  = blockIdx.y * 256 + ks * 8;

  float4 w[8];
#pragma unroll
  for (int i = 0; i < 8; ++i)
    w[i] = *(const float4*)&W1[(size_t)(k0 + i) * 512 + col];

  float4 acc[11];
#pragma unroll
  for (int r = 0; r < 11; ++r) acc[r] = make_float4(0.f, 0.f, 0.f, 0.f);

  {
    const float4 a = *(const float4*)&xn[k0];
    const float4 b = *(const float4*)&xn[k0 + 4];
    fma8(w, a, b, acc[0]);
  }
#pragma unroll
  for (int r = 0; r < 10; ++r) {
    const float4 a = *(const float4*)&xe[r * 8192 + k0];
    const float4 b = *(const float4*)&xe[r * 8192 + k0 + 4];
    fma8(w, a, b, acc[r + 1]);
  }

#pragma unroll
  for (int r = 0; r < 11; ++r)
    *(float4*)&red[(r * 32 + ks) * 36 + cg * 4] = acc[r];
  __syncthreads();

  for (int o = threadIdx.x; o < 352; o += 256) {
    const int r = o >> 5, c = o & 31;
    float s = 0.f;
#pragma unroll
    for (int k = 0; k < 32; ++k) s += red[(r * 32 + k) * 36 + c];
    p1[((size_t)blockIdx.y * 11 + r) * 512 + blockIdx.x * 32 + c] = s;
  }
}

// ------- H1 = relu(b1 + sum_ch p1): 32 blocks x 256 (176 active) -------------
// Each thread: one output, 32 fully-unrolled coalesced loads (all in flight).
__global__ __launch_bounds__(256) void k_h1(const float* __restrict__ p1,
                                            const float* __restrict__ b1,
                                            float* __restrict__ H1) {
  const int t = threadIdx.x;
  if (t >= 176) return;
  const int o = blockIdx.x * 176 + t;  // 32*176 = 5632
  float s = b1[o & 511];
#pragma unroll
  for (int ch = 0; ch < 32; ++ch) s += p1[(size_t)ch * 5632 + o];
  H1[o] = fmaxf(s, 0.f);
}

// ------- H2 partials: 32 blocks = 8 col-groups x 4 k-groups ------------------
// Block (cg,kg): cols [32cg,32cg+32), k in [128kg,128kg+128). W2 reads 128 B
// coalesced per 32-lane group; H1 k-slice staged in LDS (broadcast reads).
__global__ __launch_bounds__(256) void k_h2(const float* __restrict__ H1,
                                            const float* __restrict__ W2,
                                            float* __restrict__ p2) {
  __shared__ float h1s[11 * 128];     //  5632 B
  __shared__ float red[8 * 11 * 33];  // 11616 B
  const int t = threadIdx.x;
  const int cg = blockIdx.x & 7, kg = blockIdx.x >> 3;

  for (int i = t; i < 1408; i += 256)
    h1s[i] = H1[(i >> 7) * 512 + kg * 128 + (i & 127)];
  __syncthreads();

  const int c = t & 31, ks = t >> 5;  // 32 cols x 8 k-subs of 16
  const int col = cg * 32 + c;
  float acc[11];
#pragma unroll
  for (int r = 0; r < 11; ++r) acc[r] = 0.f;
#pragma unroll
  for (int kk = 0; kk < 16; ++kk) {
    const int kl = ks * 16 + kk;
    const float w = W2[(size_t)(kg * 128 + kl) * 256 + col];
#pragma unroll
    for (int r = 0; r < 11; ++r) acc[r] = fmaf(h1s[r * 128 + kl], w, acc[r]);
  }
#pragma unroll
  for (int r = 0; r < 11; ++r) red[(ks * 11 + r) * 33 + c] = acc[r];
  __syncthreads();
  for (int o = t; o < 352; o += 256) {
    const int r = o >> 5, cc = o & 31;
    float s = 0.f;
#pragma unroll
    for (int k = 0; k < 8; ++k) s += red[(k * 11 + r) * 33 + cc];
    p2[(kg * 11 + r) * 256 + cg * 32 + cc] = s;
  }
}

// ------- enc = relu(H2)@W3 + b3: 8 blocks x 16 cols --------------------------
// Stage: H2 = relu(b2 + sum_kg p2) into LDS (p2 44 coalesced loads/thread).
__global__ __launch_bounds__(256) void k_enc(const float* __restrict__ p2,
                                             const float* __restrict__ b2,
                                             const float* __restrict__ W3,
                                             const float* __restrict__ b3,
                                             float* __restrict__ enc) {
  __shared__ float h2s[11 * 256];      // 11264 B
  __shared__ float red[16 * 11 * 17];  // 11968 B
  const int t = threadIdx.x;
  const int j = blockIdx.x;

  {
    float s[11];
#pragma unroll
    for (int r = 0; r < 11; ++r) {
      s[r] = b2[t];
#pragma unroll
      for (int kg = 0; kg < 4; ++kg) s[r] += p2[(kg * 11 + r) * 256 + t];
    }
#pragma unroll
    for (int r = 0; r < 11; ++r) h2s[r * 256 + t] = fmaxf(s[r], 0.f);
  }
  __syncthreads();

  const int c = t & 15, ks = t >> 4;  // 16 cols x 16 k-subs of 16
  const int col = j * 16 + c;
  float acc[11];
#pragma unroll
  for (int r = 0; r < 11; ++r) acc[r] = 0.f;
#pragma unroll
  for (int kk = 0; kk < 16; ++kk) {
    const int k = ks * 16 + kk;
    const float w = W3[(size_t)k * 128 + col];
#pragma unroll
    for (int r = 0; r < 11; ++r) acc[r] = fmaf(h2s[r * 256 + k], w, acc[r]);
  }
#pragma unroll
  for (int r = 0; r < 11; ++r) red[(ks * 11 + r) * 17 + c] = acc[r];
  __syncthreads();
  if (t < 176) {
    const int r = t >> 4, cc = t & 15;
    float s = b3[j * 16 + cc];
#pragma unroll
    for (int k = 0; k < 16; ++k) s += red[(k * 11 + r) * 17 + cc];
    enc[r * 128 + j * 16 + cc] = s;
  }
}

// ------- Final: similarity + integrator. 1 block x 128, reads ~48 KB ---------
__global__ __launch_bounds__(128) void k_fin(
    const float* __restrict__ enc, const float* __restrict__ mm,
    const float* __restrict__ Wi1, const float* __restrict__ bi1,
    const float* __restrict__ Wi2, const float* __restrict__ bi2,
    const float* __restrict__ Wi3, const float* __restrict__ bi3,
    float* __restrict__ out) {
  __shared__ float encs[1408];
  __shared__ float comb[134];
  __shared__ float h1b[64];
  const int t = threadIdx.x;

  for (int i = t; i < 352; i += 128)
    *(float4*)&encs[i * 4] = *(const float4*)&enc[i * 4];
  __syncthreads();

  float consist = 0.f;
  float n0 = 0.f, n1 = 0.f;
  if (t < 64) {
    n0 = encs[t]; n1 = encs[64 + t];
    comb[t] = n0; comb[64 + t] = n1;
    if (t < 6) comb[128 + t] = mm[t];
  }
  __syncthreads();  // comb ready
  if (t < 64) {
    // wave 0: similarity (concurrent with wave 1's MLP layer 1)
    const float nn = wredsum(n0 * n0 + n1 * n1);
#pragma unroll
    for (int r = 1; r <= 10; ++r) {
      const float e0 = encs[r * 128 + t];
      const float e1 = encs[r * 128 + 64 + t];
      const float d0 = e0 - n0, d1 = e1 - n1;
      const float g  = wredsum(d0 * d0 + d1 * d1);
      const float q  = wredsum(e0 * e0 + e1 * e1);
      const float dd = wredsum(e0 * n0 + e1 * n1);
      if (t == 0) {
        const float geo = sqrtf(g);
        const float den = fmaxf(sqrtf(nn), EPS) * fmaxf(sqrtf(q), EPS);
        consist += geo - dd / den;
      }
    }
  } else {
    // wave 1: integrator layer 1 (64 cols, coalesced 256 B Wi1 rows)
    const int tt = t - 64;
    float h = bi1[tt];
#pragma unroll 4
    for (int k = 0; k < 134; ++k) h = fmaf(comb[k], Wi1[(size_t)k * 64 + tt], h);
    h1b[tt] = fmaxf(h, 0.f);
  }
  __syncthreads();
  if (t < 64) {
    float part = 0.f;
    if (t < 32) {
      float hh = bi2[t];
#pragma unroll 8
      for (int k = 0; k < 64; ++k) hh = fmaf(h1b[k], Wi2[k * 32 + t], hh);
      part = fmaxf(hh, 0.f) * Wi3[t];
    }
    const float qual = wredsum(part);
    if (t == 0) out[0] = consist * 0.1f + expf(-(qual + bi3[0]));
  }
}

extern "C" void kernel_launch(void* const* d_in, const int* in_sizes, int n_in,
                              void* d_out, int out_size, void* d_ws, size_t ws_size,
                              hipStream_t stream) {
  (void)in_sizes; (void)n_in; (void)out_size; (void)ws_size;
  const float* xn  = (const float*)d_in[0];
  const float* xe  = (const float*)d_in[1];
  const float* mm  = (const float*)d_in[2];
  const float* W1  = (const float*)d_in[3];
  const float* b1  = (const float*)d_in[4];
  const float* W2  = (const float*)d_in[5];
  const float* b2  = (const float*)d_in[6];
  const float* W3  = (const float*)d_in[7];
  const float* b3  = (const float*)d_in[8];
  const float* Wi1 = (const float*)d_in[9];
  const float* bi1 = (const float*)d_in[10];
  const float* Wi2 = (const float*)d_in[11];
  const float* bi2 = (const float*)d_in[12];
  const float* Wi3 = (const float*)d_in[13];
  const float* bi3 = (const float*)d_in[14];
  float* out = (float*)d_out;

  char* ws = (char*)d_ws;
  float* p1  = (float*)(ws);            // 32*11*512*4 = 720896 B
  float* H1  = (float*)(ws + 720896);   // 11*512*4    =  22528 B
  float* p2  = (float*)(ws + 743424);   // 4*11*256*4  =  45056 B
  float* enc = (float*)(ws + 788480);   // 11*128*4    =   5632 B

  hipLaunchKernelGGL(k_l1,  dim3(16, 32), dim3(256), 0, stream, xn, xe, W1, p1);
  hipLaunchKernelGGL(k_h1,  dim3(32),     dim3(256), 0, stream, p1, b1, H1);
  hipLaunchKernelGGL(k_h2,  dim3(32),     dim3(256), 0, stream, H1, W2, p2);
  hipLaunchKernelGGL(k_enc, dim3(8),      dim3(256), 0, stream, p2, b2, W3, b3, enc);
  hipLaunchKernelGGL(k_fin, dim3(1),      dim3(128), 0, stream,
                     enc, mm, Wi1, bi1, Wi2, bi2, Wi3, bi3, out);
}